// Round 4
// baseline (177.404 us; speedup 1.0000x reference)
//
#include <hip/hip_runtime.h>
#include <hip/hip_bf16.h>
#include <hip/hip_fp16.h>
#include <stdint.h>

#define LOSS_IDX 8388608
#define IDX_BASE 8388609

typedef _Float16 half8 __attribute__((ext_vector_type(8)));
typedef float f32x4 __attribute__((ext_vector_type(4)));
typedef unsigned long long u64;

// ---- workspace layout (bytes) ----
#define WIN_OFF  0          // 32768 * 8   winner (key<<32 | k)
#define E2_OFF   262144     // 1024 * 4    code norms
#define EIMG_OFF 266240     // 1 MiB       frag-linear fp16 hi/lo emb image
// z-image (33.55 MB) lives in d_out[0..8388608) until k3 overwrites it.
//
// frag-linear image (16x16x32 MFMA A/B layout):
//   elem (row r, c): g=r>>4, m=r&15, cc=c>>5, quad=(c>>3)&3, j=c&7
//   ushort idx = (((g*8+cc)*2+pl)*64 + m + 16*quad)*8 + j
//   each (g,cc) = contiguous 2048 B block: DMA-able, frag read = lane*16B.

static __device__ __forceinline__ unsigned fkey(float d) {
    unsigned u = __float_as_uint(d);
    return u ^ ((unsigned)(((int)u) >> 31) | 0x80000000u);
}
// skewed LDS column index: breaks the stride-4-word 8-way pattern to <=2-way
static __device__ __forceinline__ int skq(int q) { return q + (q >> 3); }

// ---------------------------------------------------------------------------
// K0: emb -> e-image (frag-linear hi/lo), e2 norms, win init, loss=0.
// ---------------------------------------------------------------------------
__global__ __launch_bounds__(256) void k0_prep(
    const float* __restrict__ emb, float* __restrict__ e2,
    ushort* __restrict__ eimg, u64* __restrict__ win64,
    float* __restrict__ out) {
    int tid = blockIdx.x * 256 + threadIdx.x;      // 0..32767
    win64[tid] = ~0ull;
    if (tid == 0) out[LOSS_IDX] = 0.f;
    int code = tid >> 5, o = tid & 31;
    const float4 v0 = *(const float4*)&emb[code * 256 + o * 8];
    const float4 v1 = *(const float4*)&emb[code * 256 + o * 8 + 4];
    float v[8] = {v0.x, v0.y, v0.z, v0.w, v1.x, v1.y, v1.z, v1.w};
    float s = 0.f;
    half8 hi, lo;
    #pragma unroll
    for (int j = 0; j < 8; ++j) {
        s = fmaf(v[j], v[j], s);
        __half h = __float2half(v[j]);
        __half l = __float2half(v[j] - __half2float(h));
        hi[j] = *(_Float16*)&h;
        lo[j] = *(_Float16*)&l;
    }
    int g = code >> 4, m = code & 15, cc = o >> 2, quad = o & 3;
    int base = (((g * 8 + cc) * 2 + 0) * 64 + m + 16 * quad) * 8;
    *(half8*)&eimg[base] = hi;
    *(half8*)&eimg[base + 512] = lo;
    #pragma unroll
    for (int msk = 1; msk <= 16; msk <<= 1) s += __shfl_xor(s, msk, 64);
    if (o == 0) e2[code] = s;
}

// ---------------------------------------------------------------------------
// K1: z_e -> frag-linear hi/lo z-image (into d_out) + sum(z^2).
// 256 blocks x 256 thr; block = 128 q x 256 c; 8 chunks of 32 c.
// float4 global reads (512 B segments) -> skewed LDS transpose -> half8 out.
// ---------------------------------------------------------------------------
__global__ __launch_bounds__(256) void k1_zimg(
    const float* __restrict__ z_e, ushort* __restrict__ zimg,
    float* __restrict__ out) {
    __shared__ float zt[32 * 143];     // [c][skq(q)] 18304 B
    __shared__ float red[4];
    int t = threadIdx.x;
    int qbase = blockIdx.x * 128;
    int b = qbase >> 10, hw0 = qbase & 1023;
    const float* zb = z_e + b * (256 * 1024) + hw0;
    int q = t & 127, grp = t >> 7;     // grp: octs {0,1} / {2,3} of chunk
    int qa = qbase + q;
    int g = qa >> 4, m = qa & 15;
    float z2 = 0.f;
    for (int ch = 0; ch < 8; ++ch) {
        int cbase = ch * 32;
        if (ch) __syncthreads();
        #pragma unroll
        for (int p = 0; p < 4; ++p) {  // stage 32c x 128q fp32
            int u = p * 256 + t;
            int c = u >> 5, hq = u & 31;
            float4 v = *(const float4*)&zb[(cbase + c) * 1024 + hq * 4];
            int s0 = c * 143 + skq(hq * 4);
            zt[s0] = v.x; zt[s0 + 1] = v.y; zt[s0 + 2] = v.z; zt[s0 + 3] = v.w;
        }
        __syncthreads();
        #pragma unroll
        for (int oi = 0; oi < 2; ++oi) {
            int ol = grp * 2 + oi;     // oct-local 0..3
            float v[8];
            #pragma unroll
            for (int j = 0; j < 8; ++j) v[j] = zt[(ol * 8 + j) * 143 + skq(q)];
            half8 hi, lo;
            #pragma unroll
            for (int j = 0; j < 8; ++j) {
                z2 = fmaf(v[j], v[j], z2);
                __half h = __float2half(v[j]);
                __half l = __float2half(v[j] - __half2float(h));
                hi[j] = *(_Float16*)&h;
                lo[j] = *(_Float16*)&l;
            }
            int oabs = (cbase >> 3) + ol;   // 0..31
            int base = (((g * 8 + (oabs >> 2)) * 2 + 0) * 64 + m + 16 * (oabs & 3)) * 8;
            *(half8*)&zimg[base] = hi;
            *(half8*)&zimg[base + 512] = lo;
        }
    }
    #pragma unroll
    for (int off = 32; off > 0; off >>= 1) z2 += __shfl_down(z2, off, 64);
    if ((t & 63) == 0) red[t >> 6] = z2;
    __syncthreads();
    if (t == 0) {
        float s = red[0] + red[1] + red[2] + red[3];
        atomicAdd(&out[LOSS_IDX], s * (1.25f / 8388608.f));
    }
}

// ---------------------------------------------------------------------------
// K2: MFMA distance GEMM + argmin. 2048 blocks x 256 thr (4 waves).
// Block tile 128q x 128k; wave tile 64x64 (mt4 x nt4); LDS 32 KB -> 4 blk/CU.
// bid = cg*256 + qg so the 8 cg-siblings of a qg share an XCD (z L2 reuse).
// ---------------------------------------------------------------------------
__global__ __launch_bounds__(256, 4) void k2_mfma(
    const ushort* __restrict__ zimg, const ushort* __restrict__ eimg,
    const float* __restrict__ e2g, u64* __restrict__ win64) {
    __shared__ __attribute__((aligned(16))) ushort as_[8192];   // 16 KB
    __shared__ __attribute__((aligned(16))) ushort bs_[8192];   // 16 KB
    int t = threadIdx.x;
    int lane = t & 63, w = t >> 6;
    int cg = blockIdx.x >> 8;       // 0..7   (128 codes)
    int qg = blockIdx.x & 255;      // 0..255 (128 queries)
    int qh = w >> 1, nh = w & 1;

    f32x4 acc[4][4];
    #pragma unroll
    for (int mt = 0; mt < 4; ++mt)
        #pragma unroll
        for (int nt = 0; nt < 4; ++nt) acc[mt][nt] = (f32x4){0.f, 0.f, 0.f, 0.f};

    for (int cc = 0; cc < 8; ++cc) {
        __syncthreads();
        #pragma unroll
        for (int i = 0; i < 4; ++i) {   // A: 8 g x 2048 B
            int u = i * 256 + t;
            int gl = u >> 7, inner = u & 127;
            const char* src = (const char*)zimg +
                (size_t)((qg * 8 + gl) * 8 + cc) * 2048 + inner * 16;
            __builtin_amdgcn_global_load_lds(
                (const __attribute__((address_space(1))) unsigned int*)src,
                (__attribute__((address_space(3))) unsigned int*)((char*)as_ + u * 16),
                16, 0, 0);
        }
        #pragma unroll
        for (int i = 0; i < 4; ++i) {   // B: 8 g x 2048 B
            int u = i * 256 + t;
            int gl = u >> 7, inner = u & 127;
            const char* src = (const char*)eimg +
                (size_t)((cg * 8 + gl) * 8 + cc) * 2048 + inner * 16;
            __builtin_amdgcn_global_load_lds(
                (const __attribute__((address_space(1))) unsigned int*)src,
                (__attribute__((address_space(3))) unsigned int*)((char*)bs_ + u * 16),
                16, 0, 0);
        }
        __syncthreads();
        half8 bh[4], bl[4];
        #pragma unroll
        for (int nt = 0; nt < 4; ++nt) {
            int ngl = nh * 4 + nt;
            bh[nt] = *(const half8*)&bs_[(ngl * 128 + lane) * 8];
            bl[nt] = *(const half8*)&bs_[(ngl * 128 + 64 + lane) * 8];
        }
        #pragma unroll
        for (int mt = 0; mt < 4; ++mt) {
            int gl = qh * 4 + mt;
            half8 ah = *(const half8*)&as_[(gl * 128 + lane) * 8];
            half8 al = *(const half8*)&as_[(gl * 128 + 64 + lane) * 8];
            #pragma unroll
            for (int nt = 0; nt < 4; ++nt) {
                acc[mt][nt] = __builtin_amdgcn_mfma_f32_16x16x32_f16(ah, bh[nt], acc[mt][nt], 0, 0, 0);
                acc[mt][nt] = __builtin_amdgcn_mfma_f32_16x16x32_f16(ah, bl[nt], acc[mt][nt], 0, 0, 0);
                acc[mt][nt] = __builtin_amdgcn_mfma_f32_16x16x32_f16(al, bh[nt], acc[mt][nt], 0, 0, 0);
            }
        }
    }

    // argmin epilogue (C layout: col=lane&15 -> code, row=(lane>>4)*4+reg -> q)
    int lm = lane & 15, lg = lane >> 4;
    float e2v[4];
    #pragma unroll
    for (int nt = 0; nt < 4; ++nt)
        e2v[nt] = e2g[cg * 128 + (nh * 4 + nt) * 16 + lm];
    #pragma unroll
    for (int mt = 0; mt < 4; ++mt)
        #pragma unroll
        for (int r = 0; r < 4; ++r) {
            u64 best = ~0ull;
            #pragma unroll
            for (int nt = 0; nt < 4; ++nt) {
                float d = fmaf(-2.f, acc[mt][nt][r], e2v[nt]);
                u64 p = ((u64)fkey(d) << 32) |
                        (unsigned)(cg * 128 + (nh * 4 + nt) * 16 + lm);
                if (p < best) best = p;
            }
            #pragma unroll
            for (int msk = 1; msk <= 8; msk <<= 1) {
                unsigned blo = __shfl_xor((unsigned)best, msk, 64);
                unsigned bhi = __shfl_xor((unsigned)(best >> 32), msk, 64);
                u64 p = ((u64)bhi << 32) | blo;
                if (p < best) best = p;
            }
            if (lm == 0)
                atomicMin(&win64[qg * 128 + qh * 64 + mt * 16 + lg * 4 + r], best);
        }
}

// ---------------------------------------------------------------------------
// K3: res = emb[k*] scatter + indices + loss part 2 (from winner key:
// d'win = e2 - 2 z.e = (zq-z)^2 - z^2). 256 blocks x 256 thr; 128 q/block.
// emb rows gathered float4 into skewed c-major LDS; float4 stores along hw.
// ---------------------------------------------------------------------------
__global__ __launch_bounds__(256) void k3_out(
    const float* __restrict__ emb, const u64* __restrict__ win64,
    float* __restrict__ out) {
    __shared__ float lds[64 * 143];    // [c][skq(q)] 36608 B
    __shared__ int lwin[128];
    __shared__ float red[2];
    int t = threadIdx.x;
    int qbase = blockIdx.x * 128;
    int b = qbase >> 10, hw0 = qbase & 1023;
    if (t < 128) {
        u64 p = win64[qbase + t];
        int k = (int)(p & 0xFFFFFFFFull);
        lwin[t] = k;
        out[IDX_BASE + qbase + t] = (float)k;
        unsigned key = (unsigned)(p >> 32);
        unsigned u = (key & 0x80000000u) ? (key ^ 0x80000000u) : ~key;
        float dval = __uint_as_float(u);
        #pragma unroll
        for (int off = 32; off > 0; off >>= 1) dval += __shfl_down(dval, off, 64);
        if ((t & 63) == 0) red[t >> 6] = dval;
    }
    __syncthreads();
    if (t == 0)
        atomicAdd(&out[LOSS_IDX], (red[0] + red[1]) * (1.25f / 8388608.f));
    float* rb = out + b * (256 * 1024) + hw0;
    for (int ch = 0; ch < 4; ++ch) {
        int cbase = ch * 64;
        if (ch) __syncthreads();
        #pragma unroll
        for (int p8 = 0; p8 < 8; ++p8) {   // gather 128 rows x 64 c
            int row = p8 * 16 + (t >> 4), cq = t & 15;
            float4 v = *(const float4*)&emb[lwin[row] * 256 + cbase + cq * 4];
            int pr = skq(row);             // row + (row>>3): 2-way banks
            int c0 = cq * 4;
            lds[(c0 + 0) * 143 + pr] = v.x;
            lds[(c0 + 1) * 143 + pr] = v.y;
            lds[(c0 + 2) * 143 + pr] = v.z;
            lds[(c0 + 3) * 143 + pr] = v.w;
        }
        __syncthreads();
        int l = t & 63, wv = t >> 6;
        #pragma unroll
        for (int i = 0; i < 8; ++i) {      // store: float4 along hw
            int c = wv * 16 + i * 2 + (l >> 5);
            int q4 = (l & 31) * 4;
            float4 o;
            o.x = lds[c * 143 + skq(q4 + 0)];
            o.y = lds[c * 143 + skq(q4 + 1)];
            o.z = lds[c * 143 + skq(q4 + 2)];
            o.w = lds[c * 143 + skq(q4 + 3)];
            *(float4*)&rb[(cbase + c) * 1024 + q4] = o;
        }
    }
}

// ---------------------------------------------------------------------------
extern "C" void kernel_launch(void* const* d_in, const int* in_sizes, int n_in,
                              void* d_out, int out_size, void* d_ws, size_t ws_size,
                              hipStream_t stream) {
    const float* z_e = (const float*)d_in[0];   // (32,256,32,32) fp32
    const float* emb = (const float*)d_in[1];   // (1024,256) fp32
    float* out = (float*)d_out;
    u64*    win  = (u64*)((char*)d_ws + WIN_OFF);
    float*  e2   = (float*)((char*)d_ws + E2_OFF);
    ushort* eimg = (ushort*)((char*)d_ws + EIMG_OFF);
    ushort* zimg = (ushort*)d_out;              // scratch until k3 overwrites

    k0_prep<<<128, 256, 0, stream>>>(emb, e2, eimg, win, out);
    k1_zimg<<<256, 256, 0, stream>>>(z_e, zimg, out);
    k2_mfma<<<2048, 256, 0, stream>>>(zimg, eimg, e2, win);
    k3_out <<<256, 256, 0, stream>>>(emb, win, out);
}

// Round 5
// 162.491 us; speedup vs baseline: 1.0918x; 1.0918x over previous
//
#include <hip/hip_runtime.h>
#include <hip/hip_bf16.h>
#include <hip/hip_fp16.h>
#include <stdint.h>

#define LOSS_IDX 8388608
#define IDX_BASE 8388609

typedef _Float16 half8 __attribute__((ext_vector_type(8)));
typedef float f32x4 __attribute__((ext_vector_type(4)));
typedef unsigned long long u64;

// ---- workspace layout (bytes) ----
#define WIN_OFF  0          // 32768 q * 4 cg * 8 B  per-cg winner partials
#define E2_OFF   1048576    // 1024 * 4    code norms
#define EIMG_OFF 1052672    // 1 MiB       frag-linear fp16 hi/lo emb image
// z-image (33.55 MB) lives in d_out[0..8388608) until k3 overwrites it.
//
// frag-linear image (16x16x32 MFMA A/B layout):
//   elem (row r, c): g=r>>4, m=r&15, cc=c>>5, quad=(c>>3)&3, j=c&7
//   ushort idx = (((g*8+cc)*2+pl)*64 + m + 16*quad)*8 + j
//   each (g,cc) = contiguous 2048 B block: DMA-able, frag read = lane*16B.

static __device__ __forceinline__ unsigned fkey(float d) {
    unsigned u = __float_as_uint(d);
    return u ^ ((unsigned)(((int)u) >> 31) | 0x80000000u);
}
static __device__ __forceinline__ int skq(int q) { return q + (q >> 3); }

// ---------------------------------------------------------------------------
// K0: emb -> e-image (frag-linear hi/lo), e2 norms, loss=0.
// ---------------------------------------------------------------------------
__global__ __launch_bounds__(256) void k0_prep(
    const float* __restrict__ emb, float* __restrict__ e2,
    ushort* __restrict__ eimg, float* __restrict__ out) {
    int tid = blockIdx.x * 256 + threadIdx.x;      // 0..32767
    if (tid == 0) out[LOSS_IDX] = 0.f;
    int code = tid >> 5, o = tid & 31;
    const float4 v0 = *(const float4*)&emb[code * 256 + o * 8];
    const float4 v1 = *(const float4*)&emb[code * 256 + o * 8 + 4];
    float v[8] = {v0.x, v0.y, v0.z, v0.w, v1.x, v1.y, v1.z, v1.w};
    float s = 0.f;
    half8 hi, lo;
    #pragma unroll
    for (int j = 0; j < 8; ++j) {
        s = fmaf(v[j], v[j], s);
        __half h = __float2half(v[j]);
        __half l = __float2half(v[j] - __half2float(h));
        hi[j] = *(_Float16*)&h;
        lo[j] = *(_Float16*)&l;
    }
    int g = code >> 4, m = code & 15, cc = o >> 2, quad = o & 3;
    int base = (((g * 8 + cc) * 2 + 0) * 64 + m + 16 * quad) * 8;
    *(half8*)&eimg[base] = hi;
    *(half8*)&eimg[base + 512] = lo;
    #pragma unroll
    for (int msk = 1; msk <= 16; msk <<= 1) s += __shfl_xor(s, msk, 64);
    if (o == 0) e2[code] = s;
}

// ---------------------------------------------------------------------------
// K1: z_e -> frag-linear hi/lo z-image (into d_out) + sum(z^2).
// 512 blocks x 256 thr; block = 128 q x 128 c (half the channels).
// ---------------------------------------------------------------------------
__global__ __launch_bounds__(256) void k1_zimg(
    const float* __restrict__ z_e, ushort* __restrict__ zimg,
    float* __restrict__ out) {
    __shared__ float zt[32 * 143];     // [c][skq(q)] 18304 B
    __shared__ float red[4];
    int t = threadIdx.x;
    int qbase = (blockIdx.x >> 1) * 128;
    int half = blockIdx.x & 1;
    int b = qbase >> 10, hw0 = qbase & 1023;
    const float* zb = z_e + b * (256 * 1024) + hw0;
    int q = t & 127, grp = t >> 7;
    int qa = qbase + q;
    int g = qa >> 4, m = qa & 15;
    float z2 = 0.f;
    for (int chi = 0; chi < 4; ++chi) {
        int ch = half * 4 + chi;
        int cbase = ch * 32;
        if (chi) __syncthreads();
        #pragma unroll
        for (int p = 0; p < 4; ++p) {  // stage 32c x 128q fp32
            int u = p * 256 + t;
            int c = u >> 5, hq = u & 31;
            float4 v = *(const float4*)&zb[(cbase + c) * 1024 + hq * 4];
            int s0 = c * 143 + skq(hq * 4);
            zt[s0] = v.x; zt[s0 + 1] = v.y; zt[s0 + 2] = v.z; zt[s0 + 3] = v.w;
        }
        __syncthreads();
        #pragma unroll
        for (int oi = 0; oi < 2; ++oi) {
            int ol = grp * 2 + oi;
            float v[8];
            #pragma unroll
            for (int j = 0; j < 8; ++j) v[j] = zt[(ol * 8 + j) * 143 + skq(q)];
            half8 hi, lo;
            #pragma unroll
            for (int j = 0; j < 8; ++j) {
                z2 = fmaf(v[j], v[j], z2);
                __half h = __float2half(v[j]);
                __half l = __float2half(v[j] - __half2float(h));
                hi[j] = *(_Float16*)&h;
                lo[j] = *(_Float16*)&l;
            }
            int oabs = (cbase >> 3) + ol;
            int base = (((g * 8 + (oabs >> 2)) * 2 + 0) * 64 + m + 16 * (oabs & 3)) * 8;
            *(half8*)&zimg[base] = hi;
            *(half8*)&zimg[base + 512] = lo;
        }
    }
    #pragma unroll
    for (int off = 32; off > 0; off >>= 1) z2 += __shfl_down(z2, off, 64);
    if ((t & 63) == 0) red[t >> 6] = z2;
    __syncthreads();
    if (t == 0) {
        float s = red[0] + red[1] + red[2] + red[3];
        atomicAdd(&out[LOSS_IDX], s * (1.25f / 8388608.f));
    }
}

// ---------------------------------------------------------------------------
// K2: MFMA distance GEMM + argmin, double-buffered LDS pipeline.
// 1024 blocks x 512 thr (8 waves). Block tile 128q x 256k; wave 64q x 64k.
// LDS 96 KB (A/B x2) -> 1 block/CU; DMA(cc+1) issued after the barrier that
// consumes DMA(cc): the vmcnt(0) drain at the next barrier only sees loads
// that had a full compute phase in flight.
// Winner: LDS-atomic merge -> plain store to per-cg partial (no global RMW).
// ---------------------------------------------------------------------------
__global__ __launch_bounds__(512, 2) void k2_mfma(
    const ushort* __restrict__ zimg, const ushort* __restrict__ eimg,
    const float* __restrict__ e2g, u64* __restrict__ winpart) {
    __shared__ __attribute__((aligned(16))) ushort as_[2][8192];    // 32 KB
    __shared__ __attribute__((aligned(16))) ushort bs_[2][16384];   // 64 KB
    __shared__ u64 winb[128];
    int t = threadIdx.x;
    int lane = t & 63, w = t >> 6;
    int bid = blockIdx.x;
    int qg = ((bid >> 5) << 3) | (bid & 7);   // 4 cg-siblings share an XCD
    int cg = (bid >> 3) & 3;
    int qh = w >> 2, nh = w & 3;              // wave: q[qh*64..], k[nh*64..]

    if (t < 128) winb[t] = ~0ull;

    f32x4 acc[4][4];
    #pragma unroll
    for (int mt = 0; mt < 4; ++mt)
        #pragma unroll
        for (int nt = 0; nt < 4; ++nt) acc[mt][nt] = (f32x4){0.f, 0.f, 0.f, 0.f};

    // ---- DMA issue for chunk cc into buffer p ----
    auto issue = [&](int cc, int p) {
        #pragma unroll
        for (int i = 0; i < 2; ++i) {         // A: 8 g x 2048 B
            int u = i * 512 + t;
            int gl = u >> 7, inner = u & 127;
            const char* src = (const char*)zimg +
                (size_t)((qg * 8 + gl) * 8 + cc) * 2048 + inner * 16;
            __builtin_amdgcn_global_load_lds(
                (const __attribute__((address_space(1))) unsigned int*)src,
                (__attribute__((address_space(3))) unsigned int*)((char*)as_[p] + u * 16),
                16, 0, 0);
        }
        #pragma unroll
        for (int i = 0; i < 4; ++i) {         // B: 16 g x 2048 B
            int u = i * 512 + t;
            int gl = u >> 7, inner = u & 127;
            const char* src = (const char*)eimg +
                (size_t)((cg * 16 + gl) * 8 + cc) * 2048 + inner * 16;
            __builtin_amdgcn_global_load_lds(
                (const __attribute__((address_space(1))) unsigned int*)src,
                (__attribute__((address_space(3))) unsigned int*)((char*)bs_[p] + u * 16),
                16, 0, 0);
        }
    };

    issue(0, 0);
    for (int cc = 0; cc < 8; ++cc) {
        int cur = cc & 1;
        __syncthreads();                      // drains DMA(cc); winb visible
        if (cc < 7) issue(cc + 1, cur ^ 1);
        const ushort* ab = as_[cur];
        const ushort* bb = bs_[cur];
        half8 ah[4], al[4];
        #pragma unroll
        for (int mt = 0; mt < 4; ++mt) {
            int gl = qh * 4 + mt;
            ah[mt] = *(const half8*)&ab[(gl * 128 + lane) * 8];
            al[mt] = *(const half8*)&ab[(gl * 128 + 64 + lane) * 8];
        }
        #pragma unroll
        for (int nt = 0; nt < 4; ++nt) {
            int ngl = nh * 4 + nt;
            half8 bh = *(const half8*)&bb[(ngl * 128 + lane) * 8];
            half8 bl = *(const half8*)&bb[(ngl * 128 + 64 + lane) * 8];
            #pragma unroll
            for (int mt = 0; mt < 4; ++mt) {
                acc[mt][nt] = __builtin_amdgcn_mfma_f32_16x16x32_f16(ah[mt], bh, acc[mt][nt], 0, 0, 0);
                acc[mt][nt] = __builtin_amdgcn_mfma_f32_16x16x32_f16(ah[mt], bl, acc[mt][nt], 0, 0, 0);
                acc[mt][nt] = __builtin_amdgcn_mfma_f32_16x16x32_f16(al[mt], bh, acc[mt][nt], 0, 0, 0);
            }
        }
    }

    // argmin epilogue (C layout: col=lane&15 -> code, row=(lane>>4)*4+r -> q)
    int lm = lane & 15, lg = lane >> 4;
    float e2v[4];
    #pragma unroll
    for (int nt = 0; nt < 4; ++nt)
        e2v[nt] = e2g[cg * 256 + nh * 64 + nt * 16 + lm];
    #pragma unroll
    for (int mt = 0; mt < 4; ++mt)
        #pragma unroll
        for (int r = 0; r < 4; ++r) {
            u64 best = ~0ull;
            #pragma unroll
            for (int nt = 0; nt < 4; ++nt) {
                float d = fmaf(-2.f, acc[mt][nt][r], e2v[nt]);
                u64 p = ((u64)fkey(d) << 32) |
                        (unsigned)(cg * 256 + nh * 64 + nt * 16 + lm);
                if (p < best) best = p;
            }
            #pragma unroll
            for (int msk = 1; msk <= 8; msk <<= 1) {
                unsigned blo = __shfl_xor((unsigned)best, msk, 64);
                unsigned bhi = __shfl_xor((unsigned)(best >> 32), msk, 64);
                u64 p = ((u64)bhi << 32) | blo;
                if (p < best) best = p;
            }
            if (lm == 0)
                atomicMin(&winb[qh * 64 + mt * 16 + lg * 4 + r], best);
        }
    __syncthreads();
    if (t < 128)
        winpart[(size_t)(qg * 128 + t) * 4 + cg] = winb[t];
}

// ---------------------------------------------------------------------------
// K3: merge per-cg winners; res = emb[k*] scatter + indices + loss part 2
// (d'win = e2 - 2 z.e = (zq-z)^2 - z^2). 512 blocks x 256 thr;
// block = 128 q x 128 c (half the channels); half 0 writes idx+loss.
// ---------------------------------------------------------------------------
__global__ __launch_bounds__(256) void k3_out(
    const float* __restrict__ emb, const u64* __restrict__ winpart,
    float* __restrict__ out) {
    __shared__ float lds[64 * 143];    // [c][skq(q)] 36608 B
    __shared__ int lwin[128];
    __shared__ float red[2];
    int t = threadIdx.x;
    int qbase = (blockIdx.x >> 1) * 128;
    int half = blockIdx.x & 1;
    int b = qbase >> 10, hw0 = qbase & 1023;
    if (t < 128) {
        const u64* wp = &winpart[(size_t)(qbase + t) * 4];
        u64 best = wp[0];
        if (wp[1] < best) best = wp[1];
        if (wp[2] < best) best = wp[2];
        if (wp[3] < best) best = wp[3];
        int k = (int)(best & 0xFFFFFFFFull);
        lwin[t] = k;
        if (half == 0) out[IDX_BASE + qbase + t] = (float)k;
        unsigned key = (unsigned)(best >> 32);
        unsigned u = (key & 0x80000000u) ? (key ^ 0x80000000u) : ~key;
        float dval = __uint_as_float(u);
        #pragma unroll
        for (int off = 32; off > 0; off >>= 1) dval += __shfl_down(dval, off, 64);
        if ((t & 63) == 0) red[t >> 6] = dval;
    }
    __syncthreads();
    if (t == 0 && half == 0)
        atomicAdd(&out[LOSS_IDX], (red[0] + red[1]) * (1.25f / 8388608.f));
    float* rb = out + b * (256 * 1024) + hw0;
    for (int chi = 0; chi < 2; ++chi) {
        int cbase = (half * 2 + chi) * 64;
        if (chi) __syncthreads();
        #pragma unroll
        for (int p8 = 0; p8 < 8; ++p8) {   // gather 128 rows x 64 c
            int row = p8 * 16 + (t >> 4), cq = t & 15;
            float4 v = *(const float4*)&emb[lwin[row] * 256 + cbase + cq * 4];
            int pr = skq(row);
            int c0 = cq * 4;
            lds[(c0 + 0) * 143 + pr] = v.x;
            lds[(c0 + 1) * 143 + pr] = v.y;
            lds[(c0 + 2) * 143 + pr] = v.z;
            lds[(c0 + 3) * 143 + pr] = v.w;
        }
        __syncthreads();
        int l = t & 63, wv = t >> 6;
        #pragma unroll
        for (int i = 0; i < 8; ++i) {      // store: float4 along hw
            int c = wv * 16 + i * 2 + (l >> 5);
            int q4 = (l & 31) * 4;
            float4 o;
            o.x = lds[c * 143 + skq(q4 + 0)];
            o.y = lds[c * 143 + skq(q4 + 1)];
            o.z = lds[c * 143 + skq(q4 + 2)];
            o.w = lds[c * 143 + skq(q4 + 3)];
            *(float4*)&rb[(cbase + c) * 1024 + q4] = o;
        }
    }
}

// ---------------------------------------------------------------------------
extern "C" void kernel_launch(void* const* d_in, const int* in_sizes, int n_in,
                              void* d_out, int out_size, void* d_ws, size_t ws_size,
                              hipStream_t stream) {
    const float* z_e = (const float*)d_in[0];   // (32,256,32,32) fp32
    const float* emb = (const float*)d_in[1];   // (1024,256) fp32
    float* out = (float*)d_out;
    u64*    win  = (u64*)((char*)d_ws + WIN_OFF);
    float*  e2   = (float*)((char*)d_ws + E2_OFF);
    ushort* eimg = (ushort*)((char*)d_ws + EIMG_OFF);
    ushort* zimg = (ushort*)d_out;              // scratch until k3 overwrites

    k0_prep<<<128, 256, 0, stream>>>(emb, e2, eimg, out);
    k1_zimg<<<512, 256, 0, stream>>>(z_e, zimg, out);
    k2_mfma<<<1024, 512, 0, stream>>>(zimg, eimg, e2, win);
    k3_out <<<512, 256, 0, stream>>>(emb, win, out);
}

// Round 6
// 154.476 us; speedup vs baseline: 1.1484x; 1.0519x over previous
//
#include <hip/hip_runtime.h>
#include <hip/hip_bf16.h>
#include <hip/hip_fp16.h>
#include <stdint.h>

#define LOSS_IDX 8388608
#define IDX_BASE 8388609

typedef _Float16 half8 __attribute__((ext_vector_type(8)));
typedef float f32x4 __attribute__((ext_vector_type(4)));
typedef unsigned long long u64;

// ---- workspace layout (bytes) ----
#define WIN_OFF  0          // 32768 q * 4 cg * 8 B  per-cg winner partials
#define E2_OFF   1048576    // 1024 * 4    code norms
#define EIMG_OFF 1052672    // 1 MiB       frag-linear fp16 hi/lo emb image
#define ZSUM_OFF 2101248    // 1024 * 4    per-block sum(z^2) partials
// z-image (33.55 MB) lives in d_out[0..8388608) until k3 overwrites it.
//
// frag-linear image (16x16x32 MFMA A/B layout):
//   elem (row r, c): g=r>>4, m=r&15, cc=c>>5, quad=(c>>3)&3, j=c&7
//   ushort idx = (((g*8+cc)*2+pl)*64 + m + 16*quad)*8 + j
//   each (g,cc) = contiguous 2048 B block: DMA-able, frag read = lane*16B.

static __device__ __forceinline__ unsigned fkey(float d) {
    unsigned u = __float_as_uint(d);
    return u ^ ((unsigned)(((int)u) >> 31) | 0x80000000u);
}

// ---------------------------------------------------------------------------
// kA: fused prep.
//  blocks [0,1024):   z_e -> frag-linear hi/lo z-image, 32 q/block, plus
//                     per-block sum(z^2) partial -> zsum[bid] (plain store).
//  blocks [1024,1152): emb -> e-image + e2 norms (old k0).
// ---------------------------------------------------------------------------
__global__ __launch_bounds__(256) void kA_prep(
    const float* __restrict__ z_e, const float* __restrict__ emb,
    ushort* __restrict__ zimg, ushort* __restrict__ eimg,
    float* __restrict__ e2, float* __restrict__ zsum) {
    __shared__ float zt[64 * 33];      // [c][q] stride 33, 8448 B
    __shared__ float red[4];
    int t = threadIdx.x;
    int bid = blockIdx.x;
    if (bid >= 1024) {                 // ---- emb prep ----
        int tid2 = (bid - 1024) * 256 + t;     // 0..32767
        int code = tid2 >> 5, o = tid2 & 31;
        const float4 v0 = *(const float4*)&emb[code * 256 + o * 8];
        const float4 v1 = *(const float4*)&emb[code * 256 + o * 8 + 4];
        float v[8] = {v0.x, v0.y, v0.z, v0.w, v1.x, v1.y, v1.z, v1.w};
        float s = 0.f;
        half8 hi, lo;
        #pragma unroll
        for (int j = 0; j < 8; ++j) {
            s = fmaf(v[j], v[j], s);
            __half h = __float2half(v[j]);
            __half l = __float2half(v[j] - __half2float(h));
            hi[j] = *(_Float16*)&h;
            lo[j] = *(_Float16*)&l;
        }
        int g = code >> 4, m = code & 15, cc = o >> 2, quad = o & 3;
        int base = (((g * 8 + cc) * 2 + 0) * 64 + m + 16 * quad) * 8;
        *(half8*)&eimg[base] = hi;
        *(half8*)&eimg[base + 512] = lo;
        #pragma unroll
        for (int msk = 1; msk <= 16; msk <<= 1) s += __shfl_xor(s, msk, 64);
        if (o == 0) e2[code] = s;
        return;
    }
    // ---- z prep: 32 q x 256 c, 4 chunks of 64 c ----
    int qbase = bid * 32;
    int b = qbase >> 10, hw0 = qbase & 1023;
    const float* zb = z_e + b * (256 * 1024) + hw0;
    int q = t & 31, og = t >> 5;       // thread = (q, oct-group)
    int g = (qbase + q) >> 4, m = (qbase + q) & 15;
    float z2 = 0.f;
    for (int ch = 0; ch < 4; ++ch) {
        int cbase = ch * 64;
        if (ch) __syncthreads();
        #pragma unroll
        for (int p = 0; p < 2; ++p) {  // stage 64c x 32q fp32 (float4 reads)
            int u = p * 256 + t;
            int c = u >> 3, hq = u & 7;
            float4 v = *(const float4*)&zb[(cbase + c) * 1024 + hq * 4];
            int s0 = c * 33 + hq * 4;
            zt[s0] = v.x; zt[s0 + 1] = v.y; zt[s0 + 2] = v.z; zt[s0 + 3] = v.w;
        }
        __syncthreads();
        float v[8];
        #pragma unroll
        for (int j = 0; j < 8; ++j) v[j] = zt[(og * 8 + j) * 33 + q];
        half8 hi, lo;
        #pragma unroll
        for (int j = 0; j < 8; ++j) {
            z2 = fmaf(v[j], v[j], z2);
            __half h = __float2half(v[j]);
            __half l = __float2half(v[j] - __half2float(h));
            hi[j] = *(_Float16*)&h;
            lo[j] = *(_Float16*)&l;
        }
        int cc = ch * 2 + (og >> 2), quad = og & 3;
        int base = (((g * 8 + cc) * 2 + 0) * 64 + m + 16 * quad) * 8;
        *(half8*)&zimg[base] = hi;
        *(half8*)&zimg[base + 512] = lo;
    }
    #pragma unroll
    for (int off = 32; off > 0; off >>= 1) z2 += __shfl_down(z2, off, 64);
    if ((t & 63) == 0) red[t >> 6] = z2;
    __syncthreads();
    if (t == 0) zsum[bid] = red[0] + red[1] + red[2] + red[3];
}

// ---------------------------------------------------------------------------
// K2: MFMA distance GEMM + argmin (R3 core). 1024 blocks x 256 thr (4 waves).
// Block tile 128q x 256k; wave tile 64q x 128k; LDS 48 KB single-buffer.
// Winner: LDS-atomic merge -> plain store to per-cg partial (no global RMW).
// Block 0 also zeroes the loss slot for k3.
// ---------------------------------------------------------------------------
__global__ __launch_bounds__(256, 2) void k2_mfma(
    const ushort* __restrict__ zimg, const ushort* __restrict__ eimg,
    const float* __restrict__ e2g, u64* __restrict__ winpart,
    float* __restrict__ out) {
    __shared__ __attribute__((aligned(16))) ushort as_[8192];   // 16 KB
    __shared__ __attribute__((aligned(16))) ushort bs_[16384];  // 32 KB
    __shared__ u64 winb[128];
    int t = threadIdx.x;
    int lane = t & 63, w = t >> 6;
    int bid = blockIdx.x;
    int qg = ((bid >> 5) << 3) | (bid & 7);   // 4 cg-siblings share an XCD
    int cg = (bid >> 3) & 3;
    int qh = w >> 1, nh = w & 1;
    if (bid == 0 && t == 0) out[LOSS_IDX] = 0.f;
    if (t < 128) winb[t] = ~0ull;

    f32x4 acc[4][8];
    #pragma unroll
    for (int mt = 0; mt < 4; ++mt)
        #pragma unroll
        for (int nt = 0; nt < 8; ++nt) acc[mt][nt] = (f32x4){0.f, 0.f, 0.f, 0.f};

    for (int cc = 0; cc < 8; ++cc) {
        __syncthreads();
        #pragma unroll
        for (int i = 0; i < 4; ++i) {   // A: 8 g x 2048 B
            int u = i * 256 + t;
            int gl = u >> 7, inner = u & 127;
            const char* src = (const char*)zimg +
                (size_t)((qg * 8 + gl) * 8 + cc) * 2048 + inner * 16;
            __builtin_amdgcn_global_load_lds(
                (const __attribute__((address_space(1))) unsigned int*)src,
                (__attribute__((address_space(3))) unsigned int*)((char*)as_ + u * 16),
                16, 0, 0);
        }
        #pragma unroll
        for (int i = 0; i < 8; ++i) {   // B: 16 g x 2048 B
            int u = i * 256 + t;
            int gl = u >> 7, inner = u & 127;
            const char* src = (const char*)eimg +
                (size_t)((cg * 16 + gl) * 8 + cc) * 2048 + inner * 16;
            __builtin_amdgcn_global_load_lds(
                (const __attribute__((address_space(1))) unsigned int*)src,
                (__attribute__((address_space(3))) unsigned int*)((char*)bs_ + u * 16),
                16, 0, 0);
        }
        __syncthreads();
        half8 ah[4], al[4];
        #pragma unroll
        for (int mt = 0; mt < 4; ++mt) {
            int gl = qh * 4 + mt;
            ah[mt] = *(const half8*)&as_[(gl * 128 + lane) * 8];
            al[mt] = *(const half8*)&as_[(gl * 128 + 64 + lane) * 8];
        }
        #pragma unroll
        for (int nt = 0; nt < 8; ++nt) {
            int ngl = nh * 8 + nt;
            half8 bh = *(const half8*)&bs_[(ngl * 128 + lane) * 8];
            half8 bl = *(const half8*)&bs_[(ngl * 128 + 64 + lane) * 8];
            #pragma unroll
            for (int mt = 0; mt < 4; ++mt) {
                acc[mt][nt] = __builtin_amdgcn_mfma_f32_16x16x32_f16(ah[mt], bh, acc[mt][nt], 0, 0, 0);
                acc[mt][nt] = __builtin_amdgcn_mfma_f32_16x16x32_f16(ah[mt], bl, acc[mt][nt], 0, 0, 0);
                acc[mt][nt] = __builtin_amdgcn_mfma_f32_16x16x32_f16(al[mt], bh, acc[mt][nt], 0, 0, 0);
            }
        }
    }

    // argmin epilogue (C layout: col=lane&15 -> code, row=(lane>>4)*4+r -> q)
    int lm = lane & 15, lg = lane >> 4;
    float e2v[8];
    #pragma unroll
    for (int nt = 0; nt < 8; ++nt)
        e2v[nt] = e2g[cg * 256 + (nh * 8 + nt) * 16 + lm];
    #pragma unroll
    for (int mt = 0; mt < 4; ++mt)
        #pragma unroll
        for (int r = 0; r < 4; ++r) {
            u64 best = ~0ull;
            #pragma unroll
            for (int nt = 0; nt < 8; ++nt) {
                float d = fmaf(-2.f, acc[mt][nt][r], e2v[nt]);
                u64 p = ((u64)fkey(d) << 32) |
                        (unsigned)(cg * 256 + (nh * 8 + nt) * 16 + lm);
                if (p < best) best = p;
            }
            #pragma unroll
            for (int msk = 1; msk <= 8; msk <<= 1) {
                unsigned blo = __shfl_xor((unsigned)best, msk, 64);
                unsigned bhi = __shfl_xor((unsigned)(best >> 32), msk, 64);
                u64 p = ((u64)bhi << 32) | blo;
                if (p < best) best = p;
            }
            if (lm == 0)
                atomicMin(&winb[qh * 64 + mt * 16 + lg * 4 + r], best);
        }
    __syncthreads();
    if (t < 128)
        winpart[(size_t)(qg * 128 + t) * 4 + cg] = winb[t];
}

// ---------------------------------------------------------------------------
// K3: merge per-cg winners; res = emb[k*] scatter + indices + loss.
// 512 blocks x 256 thr; 64 q/block; 4 chunks of 64 c.
// loss = (sum d'win + sum z^2) * 1.25/N; d'win from winner key.
// ---------------------------------------------------------------------------
__global__ __launch_bounds__(256) void k3_out(
    const float* __restrict__ emb, const u64* __restrict__ winpart,
    const float* __restrict__ zsum, float* __restrict__ out) {
    __shared__ float lds[64 * 67];     // [c][row] stride 67, 17152 B
    __shared__ int lwin[64];
    __shared__ float dred;
    int t = threadIdx.x;
    int bid = blockIdx.x;
    int qbase = bid * 64;
    int b = qbase >> 10, hw0 = qbase & 1023;
    if (t < 64) {
        const u64* wp = &winpart[(size_t)(qbase + t) * 4];
        u64 best = wp[0];
        if (wp[1] < best) best = wp[1];
        if (wp[2] < best) best = wp[2];
        if (wp[3] < best) best = wp[3];
        int k = (int)(best & 0xFFFFFFFFull);
        lwin[t] = k;
        out[IDX_BASE + qbase + t] = (float)k;
        unsigned key = (unsigned)(best >> 32);
        unsigned u = (key & 0x80000000u) ? (key ^ 0x80000000u) : ~key;
        float dval = __uint_as_float(u);
        #pragma unroll
        for (int off = 32; off > 0; off >>= 1) dval += __shfl_down(dval, off, 64);
        if (t == 0) dred = dval;
    }
    __syncthreads();
    if (t == 0) {
        float zp = zsum[2 * bid] + zsum[2 * bid + 1];
        atomicAdd(&out[LOSS_IDX], (dred + zp) * (1.25f / 8388608.f));
    }
    float* rb = out + b * (256 * 1024) + hw0;
    for (int ch = 0; ch < 4; ++ch) {
        int cbase = ch * 64;
        if (ch) __syncthreads();
        #pragma unroll
        for (int i = 0; i < 4; ++i) {      // gather 64 rows x 64 c (float4)
            int row = i * 16 + (t >> 4), cq = t & 15;
            float4 v = *(const float4*)&emb[lwin[row] * 256 + cbase + cq * 4];
            int c0 = cq * 4;
            lds[(c0 + 0) * 67 + row] = v.x;
            lds[(c0 + 1) * 67 + row] = v.y;
            lds[(c0 + 2) * 67 + row] = v.z;
            lds[(c0 + 3) * 67 + row] = v.w;
        }
        __syncthreads();
        int l = t & 63, wv = t >> 6;
        #pragma unroll
        for (int i = 0; i < 4; ++i) {      // store: float4 along hw
            int c = wv * 16 + i * 4 + (l >> 4);
            int q4 = (l & 15) * 4;
            float4 o;
            o.x = lds[c * 67 + q4 + 0];
            o.y = lds[c * 67 + q4 + 1];
            o.z = lds[c * 67 + q4 + 2];
            o.w = lds[c * 67 + q4 + 3];
            *(float4*)&rb[(cbase + c) * 1024 + q4] = o;
        }
    }
}

// ---------------------------------------------------------------------------
extern "C" void kernel_launch(void* const* d_in, const int* in_sizes, int n_in,
                              void* d_out, int out_size, void* d_ws, size_t ws_size,
                              hipStream_t stream) {
    const float* z_e = (const float*)d_in[0];   // (32,256,32,32) fp32
    const float* emb = (const float*)d_in[1];   // (1024,256) fp32
    float* out = (float*)d_out;
    u64*    win  = (u64*)((char*)d_ws + WIN_OFF);
    float*  e2   = (float*)((char*)d_ws + E2_OFF);
    ushort* eimg = (ushort*)((char*)d_ws + EIMG_OFF);
    float*  zsum = (float*)((char*)d_ws + ZSUM_OFF);
    ushort* zimg = (ushort*)d_out;              // scratch until k3 overwrites

    kA_prep<<<1152, 256, 0, stream>>>(z_e, emb, zimg, eimg, e2, zsum);
    k2_mfma<<<1024, 256, 0, stream>>>(zimg, eimg, e2, win, out);
    k3_out <<<512, 256, 0, stream>>>(emb, win, zsum, out);
}